// Round 3
// baseline (274.484 us; speedup 1.0000x reference)
//
#include <hip/hip_runtime.h>

// GRU: B=8192 chains, T=512 steps, IN=5, H=7, fused heads.
// R9 (from R7 @127us kernel, VALUBusy 60%. R8 dual-chain/1-wave REGRESSED
// to 142us, VALUBusy 56%: 1 wave/SIMD eats every non-VALU stall alone ->
// reverted to R7's 2-wave/SIMD single-chain structure). Changes:
//  (1) LDS + barrier removed: x goes global->reg directly, 4-step chunks
//      (5 dwordx4), 4-buffer rotation, prefetch distance 3 (~12 steps
//      ~1000cy, covers HBM-cold; x (84MB) is L3-resident on warm reps).
//      Kills the per-tile barrier lockstep (both waves stalled together)
//      plus all ds_write/ds_read/staging instructions. 16 lanes of a group
//      load the same 16B -> coalesces to one request (L1 broadcast).
//  (2) head stores: per-step pointer bumps (4 VALU/step) replaced by
//      per-tile bases + compile-time offsets (3*tt / tt fold into the
//      store offset immediate).
//  (3) gate pre-scaling: matvec-lane slot0 weights/biases pre-scaled by
//      -log2(e), slot1 by -2*log2(e) -> the two v_mul feeding exp2 vanish,
//      serial chain shorter. Head lanes (l=7,15) keep raw weights.
// R7 (verified): head rows (W_m x3, W_r) ride pad lanes l=7,15 of the
// packed whh pk_fma rotation; head value = accH of those lanes, deferred
// one step (at step s store head(h_{s-1}) to index s-1; epilogue does 511).
// Layout (R4/R5, verified): 16 lanes/batch, lane l: slot0 = r row (l<8) /
// z row (l>=8), slot1 = n row (both halves); one sigmoid/lane + ror:8 swap.
// DPP anchor (R3-R8 passed): row_ror:N dst[n]=src[(n-N)mod16]; position i
// holds unit (l-i)&7; weight k=(j-i)&7, k==7 -> 0 (pad-sourced killed).

namespace {
constexpr int Bn = 8192;
constexpr int Tn = 512;
constexpr int INn = 5;
constexpr int Hn = 7;
constexpr int BPB = 16;                  // batches per block (256 thr / 16)
constexpr int NTILE = 16;                // outer loop iterations
constexpr int CPT = 8;                   // chunks per tile, 4 steps each
constexpr long long OFF_OR = (long long)Bn * Tn * 3;
constexpr long long OFF_HL = OFF_OR + (long long)Bn * Tn;
constexpr float LOG2E = 1.44269504088896340736f;
}

typedef float v2f __attribute__((ext_vector_type(2)));

__device__ __forceinline__ v2f pk_fma(v2f a, v2f b, v2f c) {
    return __builtin_elementwise_fma(a, b, c);
}
__device__ __forceinline__ v2f splat2(float x) { return (v2f){x, x}; }

template<int CTRL>
__device__ __forceinline__ float dppf(float v) {
    int r = __builtin_amdgcn_update_dpp(0, __builtin_bit_cast(int, v),
                                        CTRL, 0xF, 0xF, true);
    return __builtin_bit_cast(float, r);
}

__global__ __launch_bounds__(256, 2) void gru_fused_kernel(
    const float* __restrict__ x,     // [B, T, IN]
    const float* __restrict__ W_ih,  // [21, 5]
    const float* __restrict__ W_hh,  // [21, 7]
    const float* __restrict__ b_ih,  // [21]
    const float* __restrict__ b_hh,  // [21]
    const float* __restrict__ W_h0,  // [7, 1]
    const float* __restrict__ W_m,   // [3, 7]
    const float* __restrict__ b_m,   // [3]
    const float* __restrict__ W_r,   // [1, 7]
    const float* __restrict__ b_r,   // [1]
    float* __restrict__ out)
{
    const int tid  = threadIdx.x;
    const int l    = tid & 15;           // lane within 16-lane batch group
    const int j    = l & 7;              // hidden-unit slot (7 = pad/head lane)
    const int g    = tid >> 4;           // batch slot in block
    const int b    = blockIdx.x * BPB + g;
    const int jj   = (j < 7) ? j : 6;
    const bool lo8 = ((l & 8) == 0);
    const bool hl  = (j == 7);           // head lanes: l == 7 and l == 15
    const bool is7  = hl && lo8;         // lane 7
    const bool is15 = hl && !lo8;        // lane 15

    const float kR = -LOG2E;             // slot0 scale (sigmoid preact)
    const float kN = -2.0f * LOG2E;      // slot1 scale (tanh preact)

    // ---- rotated, packed weights ----
    // matvec lanes (j<7): slot0 = r row (lo8) / z row (hi8) [scaled kR],
    //                     slot1 = n row [scaled kN].
    // head lanes (j==7): l=7  -> slot0 = W_m row0, slot1 = W_m row1
    //                    l=15 -> slot0 = W_m row2, slot1 = W_r   (raw)
    const int row0 = lo8 ? jj : (Hn + jj);
    const int row1 = 2 * Hn + jj;

    v2f whh_rot[8];
    #pragma unroll
    for (int i = 0; i < 8; ++i) {
        const int k = (j - i) & 7;
        if (k < 7) {
            if (hl) {
                const float w0 = lo8 ? W_m[0 * Hn + k] : W_m[2 * Hn + k];
                const float w1 = lo8 ? W_m[1 * Hn + k] : W_r[k];
                whh_rot[i] = (v2f){w0, w1};
            } else {
                whh_rot[i] = (v2f){kR * W_hh[row0 * Hn + k],
                                   kN * W_hh[row1 * Hn + k]};
            }
        } else {
            whh_rot[i] = (v2f){0.0f, 0.0f};
        }
    }
    v2f wih01[INn];
    #pragma unroll
    for (int i = 0; i < INn; ++i)
        wih01[i] = hl ? (v2f){0.0f, 0.0f}
                      : (v2f){kR * W_ih[row0 * INn + i],
                              kN * W_ih[row1 * INn + i]};
    const v2f biasH = hl ? (lo8 ? (v2f){b_m[0], b_m[1]}
                                : (v2f){b_m[2], b_r[0]})
                         : (v2f){kR * b_hh[row0], kN * b_hh[row1]};
    const v2f biasP = hl ? (v2f){0.0f, 0.0f}
                         : (v2f){kR * b_ih[row0], kN * b_ih[row1]};

    float hj = W_h0[jj];

    const float4* xq = (const float4*)(x + (long long)b * (Tn * INn));
    float* om  = out + (long long)b * (Tn * 3);
    float* orr = out + OFF_OR + (long long)b * Tn;

    // ---- prologue: chunks 0..2 into buffers 0..2 (distance-3 pipeline) ----
    float4 xbuf[4][5];
    #pragma unroll
    for (int k = 0; k < 5; ++k) {
        xbuf[0][k] = xq[k];
        xbuf[1][k] = xq[5 + k];
        xbuf[2][k] = xq[10 + k];
    }

    for (int tl = 0; tl < NTILE; ++tl) {
        // per-tile store bases; offsets below are compile-time immediates.
        float* mb0 = om + (tl * 96 - 3) + (lo8 ? 0 : 2);  // slot0, lanes 7/15
        float* mb1 = om + (tl * 96 - 3) + 1;              // lane 7 slot1
        float* rb  = orr + (tl * 32 - 1);                 // lane 15 slot1
        const float4* xpre = xq + tl * (CPT * 5) + 15;    // chunk cc+3 base

        #pragma unroll
        for (int c = 0; c < CPT; ++c) {
            // prefetch chunk cc+3 (cc = tl*8+c); valid iff tl*8+c+3 < 128
            if (c <= 4 || tl + 1 < NTILE) {
                #pragma unroll
                for (int k = 0; k < 5; ++k)
                    xbuf[(c + 3) & 3][k] = xpre[c * 5 + k];
            }
            const float* xcf = (const float*)xbuf[c & 3];

            #pragma unroll
            for (int ss = 0; ss < 4; ++ss) {
                const int tt = c * 4 + ss;

                // systolic rotation: hidden matvec (packed r|z, n) and the
                // head rows (pad lanes) share one pk_fma chain.
                v2f accA = biasH;
                v2f accB = (v2f){0.0f, 0.0f};
                accA = pk_fma(whh_rot[0], splat2(hj), accA);
                {
                    float h1 = dppf<0x121>(hj);
                    accB = pk_fma(whh_rot[1], splat2(h1), accB);
                    float h2 = dppf<0x122>(hj);
                    accA = pk_fma(whh_rot[2], splat2(h2), accA);
                    float h3 = dppf<0x123>(hj);
                    accB = pk_fma(whh_rot[3], splat2(h3), accB);
                    float h4 = dppf<0x124>(hj);
                    accA = pk_fma(whh_rot[4], splat2(h4), accA);
                    float h5 = dppf<0x125>(hj);
                    accB = pk_fma(whh_rot[5], splat2(h5), accB);
                    float h6 = dppf<0x126>(hj);
                    accA = pk_fma(whh_rot[6], splat2(h6), accA);
                    float h7 = dppf<0x127>(hj);
                    accB = pk_fma(whh_rot[7], splat2(h7), accB);
                }
                v2f accH = accA + accB;      // matvec lanes: (g0,g1) scaled
                                             // head lanes: (head0, head1) raw

                // input projection (zeroed on head lanes)
                v2f accP = biasP;
                #pragma unroll
                for (int i = 0; i < INn; ++i)
                    accP = pk_fma(wih01[i], splat2(xcf[5 * ss + i]), accP);

                // deferred head(h_{s-1}) -> index s-1, offsets are imms
                if (tt > 0 || tl > 0) {
                    if (hl)   mb0[3 * tt] = accH[0];
                    if (is7)  mb1[3 * tt] = accH[1];
                    if (is15) rb[tt]      = accH[1];
                }

                // gates: preacts arrive pre-scaled by -log2e / -2log2e
                float ea = __builtin_amdgcn_exp2f(accH[0] + accP[0]);
                float s  = __builtin_amdgcn_rcpf(1.0f + ea);
                float sv = dppf<0x128>(s);       // row_ror:8 half-swap
                float rv = lo8 ? s : sv;
                float zv = lo8 ? sv : s;
                float et = __builtin_amdgcn_exp2f(fmaf(rv, accH[1], accP[1]));
                float t  = __builtin_amdgcn_rcpf(1.0f + et);
                float n  = fmaf(2.0f, t, -1.0f); // tanh
                hj = n + zv * (hj - n);          // (1-z)*n + z*h
            }
        }
    }

    // epilogue: head of final h (one more rotation), stored at index T-1
    {
        v2f accA = biasH;
        v2f accB = (v2f){0.0f, 0.0f};
        accA = pk_fma(whh_rot[0], splat2(hj), accA);
        accB = pk_fma(whh_rot[1], splat2(dppf<0x121>(hj)), accB);
        accA = pk_fma(whh_rot[2], splat2(dppf<0x122>(hj)), accA);
        accB = pk_fma(whh_rot[3], splat2(dppf<0x123>(hj)), accB);
        accA = pk_fma(whh_rot[4], splat2(dppf<0x124>(hj)), accA);
        accB = pk_fma(whh_rot[5], splat2(dppf<0x125>(hj)), accB);
        accA = pk_fma(whh_rot[6], splat2(dppf<0x126>(hj)), accA);
        accB = pk_fma(whh_rot[7], splat2(dppf<0x127>(hj)), accB);
        v2f accH = accA + accB;
        if (hl)   om[(Tn - 1) * 3 + (lo8 ? 0 : 2)] = accH[0];
        if (is7)  om[(Tn - 1) * 3 + 1]             = accH[1];
        if (is15) orr[Tn - 1]                      = accH[1];
    }

    // h_last: [1, B, H]
    if (l < Hn) out[OFF_HL + (long long)b * Hn + l] = hj;
}

extern "C" void kernel_launch(void* const* d_in, const int* in_sizes, int n_in,
                              void* d_out, int out_size, void* d_ws, size_t ws_size,
                              hipStream_t stream) {
    const float* x    = (const float*)d_in[0];
    // d_in[1] = batch_size (scalar), unused — B compiled in
    const float* W_ih = (const float*)d_in[2];
    const float* W_hh = (const float*)d_in[3];
    const float* b_ih = (const float*)d_in[4];
    const float* b_hh = (const float*)d_in[5];
    const float* W_h0 = (const float*)d_in[6];
    const float* W_m  = (const float*)d_in[7];
    const float* b_m  = (const float*)d_in[8];
    const float* W_r  = (const float*)d_in[9];
    const float* b_r  = (const float*)d_in[10];
    float* out = (float*)d_out;

    dim3 grid(Bn / BPB);  // 512 blocks
    dim3 block(256);      // 16 batch elements x 16 lanes
    gru_fused_kernel<<<grid, block, 0, stream>>>(x, W_ih, W_hh, b_ih, b_hh,
                                                 W_h0, W_m, b_m, W_r, b_r, out);
}

// Round 5
// 219.885 us; speedup vs baseline: 1.2483x; 1.2483x over previous
//
#include <hip/hip_runtime.h>

// GRU: B=8192 chains, T=512 steps, IN=5, H=7, fused heads.
// R10 = R7 skeleton (127us, VALUBusy 60%, 2 waves/SIMD, LDS x-staging) +
// verified R9 wins + LDS head buffering:
//  (1) head stores: 3 scattered exec-masked global stores/step -> one
//      ds_write2/step into a per-group LDS buffer (planar m0@0,m1@33,
//      m2@66,r@99, group stride 132 dwords: lane7 banks 4g+tt,4g+1+tt;
//      lane15 4g+2+tt,4g+3+tt -> all 16 accesses distinct banks), flushed
//      once per 32-step tile as 8 coalesced global_store_dword (16
//      consecutive dwords per group per instr). Kills TA scatter cost and
//      vmcnt entanglement of the compute loop; head ptr bumps (4 VALU/step)
//      die with it (buffer offsets are compile-time immediates).
//  (2) gate pre-scaling (R9, verified): matvec-lane slot0 weights/biases
//      pre-scaled by -log2(e), slot1 by -2log2(e) -> exp2 feed muls gone.
// R9 lesson: global-direct x broke (VGPR cap collapsed the prefetch
// pipeline -> per-chunk L2/L3 stalls, 162us). x stays in LDS (lgkmcnt,
// decoupled from store queue). R8 lesson: 1 wave/SIMD regresses; keep 2.
// R7 (verified): head rows (W_m x3, W_r) ride pad lanes l=7,15 of the
// packed whh pk_fma rotation; head of h_{s-1} surfaces at step s ->
// output index s-1; epilogue does index 511.
// Layout (R4/R5, verified): 16 lanes/batch, lane l: slot0 = r row (l<8) /
// z row (l>=8), slot1 = n row (both halves); one sigmoid/lane + ror:8 swap.
// DPP anchor (R3-R9 passed): row_ror:N dst[n]=src[(n-N)mod16]; position i
// holds unit (l-i)&7; weight k=(j-i)&7, k==7 -> 0 (pad-sourced killed).
// LDS x banks (R4): (g*164+w)%32=(4g+w)%32 -> groups of a wave occupy
// disjoint 4-dword bank ranges per b128 read.

namespace {
constexpr int Bn = 8192;
constexpr int Tn = 512;
constexpr int INn = 5;
constexpr int Hn = 7;
constexpr int TILE = 32;
constexpr int NTILE = Tn / TILE;         // 16
constexpr int BPB = 16;                  // batches per block (256 thr / 16)
constexpr int XSTR = 164;                // padded floats/batch in LDS (x)
constexpr int HSTR = 132;                // head buf stride: m0@0,m1@33,m2@66,r@99
constexpr long long OFF_OR = (long long)Bn * Tn * 3;
constexpr long long OFF_HL = OFF_OR + (long long)Bn * Tn;
constexpr float LOG2E = 1.44269504088896340736f;
}

typedef float v2f __attribute__((ext_vector_type(2)));

__device__ __forceinline__ v2f pk_fma(v2f a, v2f b, v2f c) {
    return __builtin_elementwise_fma(a, b, c);
}
__device__ __forceinline__ v2f splat2(float x) { return (v2f){x, x}; }

template<int CTRL>
__device__ __forceinline__ float dppf(float v) {
    int r = __builtin_amdgcn_update_dpp(0, __builtin_bit_cast(int, v),
                                        CTRL, 0xF, 0xF, true);
    return __builtin_bit_cast(float, r);
}

__global__ __launch_bounds__(256, 2) void gru_fused_kernel(
    const float* __restrict__ x,     // [B, T, IN]
    const float* __restrict__ W_ih,  // [21, 5]
    const float* __restrict__ W_hh,  // [21, 7]
    const float* __restrict__ b_ih,  // [21]
    const float* __restrict__ b_hh,  // [21]
    const float* __restrict__ W_h0,  // [7, 1]
    const float* __restrict__ W_m,   // [3, 7]
    const float* __restrict__ b_m,   // [3]
    const float* __restrict__ W_r,   // [1, 7]
    const float* __restrict__ b_r,   // [1]
    float* __restrict__ out)
{
    __shared__ float lds_x[2][BPB * XSTR];   // 2 x 10.25 KB
    __shared__ float lds_h[BPB * HSTR];      // 8.25 KB head ring

    const int tid  = threadIdx.x;
    const int l    = tid & 15;           // lane within 16-lane batch group
    const int j    = l & 7;              // hidden-unit slot (7 = pad/head lane)
    const int g    = tid >> 4;           // batch slot in block
    const int b    = blockIdx.x * BPB + g;
    const int jj   = (j < 7) ? j : 6;
    const bool lo8 = ((l & 8) == 0);
    const bool hl  = (j == 7);           // head lanes: l == 7 and l == 15
    const bool is15 = hl && !lo8;        // lane 15

    const float kR = -LOG2E;             // slot0 scale (sigmoid preact)
    const float kN = -2.0f * LOG2E;      // slot1 scale (tanh preact)

    // ---- rotated, packed weights ----
    // matvec lanes (j<7): slot0 = r row (lo8) / z row (hi8) [scaled kR],
    //                     slot1 = n row [scaled kN].
    // head lanes (j==7): l=7  -> slot0 = W_m row0, slot1 = W_m row1
    //                    l=15 -> slot0 = W_m row2, slot1 = W_r   (raw)
    const int row0 = lo8 ? jj : (Hn + jj);
    const int row1 = 2 * Hn + jj;

    v2f whh_rot[8];
    #pragma unroll
    for (int i = 0; i < 8; ++i) {
        const int k = (j - i) & 7;
        if (k < 7) {
            if (hl) {
                const float w0 = lo8 ? W_m[0 * Hn + k] : W_m[2 * Hn + k];
                const float w1 = lo8 ? W_m[1 * Hn + k] : W_r[k];
                whh_rot[i] = (v2f){w0, w1};
            } else {
                whh_rot[i] = (v2f){kR * W_hh[row0 * Hn + k],
                                   kN * W_hh[row1 * Hn + k]};
            }
        } else {
            whh_rot[i] = (v2f){0.0f, 0.0f};
        }
    }
    v2f wih01[INn];
    #pragma unroll
    for (int i = 0; i < INn; ++i)
        wih01[i] = hl ? (v2f){0.0f, 0.0f}
                      : (v2f){kR * W_ih[row0 * INn + i],
                              kN * W_ih[row1 * INn + i]};
    const v2f biasH = hl ? (lo8 ? (v2f){b_m[0], b_m[1]}
                                : (v2f){b_m[2], b_r[0]})
                         : (v2f){kR * b_hh[row0], kN * b_hh[row1]};
    const v2f biasP = hl ? (v2f){0.0f, 0.0f}
                         : (v2f){kR * b_ih[row0], kN * b_ih[row1]};

    float hj = W_h0[jj];

    const float* xb = x + (long long)b * (Tn * INn);
    float* om  = out + (long long)b * (Tn * 3);
    float* orr = out + OFF_OR + (long long)b * Tn;

    // head buffer bases + flush read offsets (all tile-invariant)
    float* hwb = &lds_h[g * HSTR + (is15 ? 66 : 0)];   // writer (lanes 7/15)
    const float* hrd = &lds_h[g * HSTR];               // flush reader
    int fq[6];
    #pragma unroll
    for (int i = 0; i < 6; ++i) {
        const int q = i * 16 + l;                      // output dword 0..95
        fq[i] = (q % 3) * 33 + q / 3;                  // planar -> interleaved
    }

    // ---- prologue: stage tile 0 (160 floats = 80 float2 per batch) ----
    float2 stage[5];
    #pragma unroll
    for (int i = 0; i < 5; ++i)
        stage[i] = *(const float2*)(xb + 2 * (l + 16 * i));

    int cur = 0;
    for (int tl = 0; tl < NTILE; ++tl) {
        #pragma unroll
        for (int i = 0; i < 5; ++i)
            *(float2*)&lds_x[cur][g * XSTR + 2 * (l + 16 * i)] = stage[i];
        __syncthreads();

        if (tl + 1 < NTILE) {
            const float* src = xb + (tl + 1) * (TILE * INn);
            #pragma unroll
            for (int i = 0; i < 5; ++i)
                stage[i] = *(const float2*)(src + 2 * (l + 16 * i));
        }

        // x for this tile as 8 chunks of 4 steps (20 floats = 5 float4),
        // register double-buffered: chunk c+1 loads issue while c computes.
        const float4* xq = (const float4*)&lds_x[cur][g * XSTR];
        float4 xbuf[2][5];
        #pragma unroll
        for (int k = 0; k < 5; ++k) xbuf[0][k] = xq[k];

        #pragma unroll
        for (int c = 0; c < 8; ++c) {
            if (c < 7) {
                #pragma unroll
                for (int k = 0; k < 5; ++k)
                    xbuf[(c + 1) & 1][k] = xq[(c + 1) * 5 + k];
            }
            const float* xcf = (const float*)xbuf[c & 1];

            #pragma unroll
            for (int ss = 0; ss < 4; ++ss) {
                const int tt = c * 4 + ss;     // 0..31, compile-time

                // systolic rotation: hidden matvec (packed r|z, n) and the
                // head rows (pad lanes) share one pk_fma chain.
                v2f accA = biasH;
                v2f accB = (v2f){0.0f, 0.0f};
                accA = pk_fma(whh_rot[0], splat2(hj), accA);
                {
                    float h1 = dppf<0x121>(hj);
                    accB = pk_fma(whh_rot[1], splat2(h1), accB);
                    float h2 = dppf<0x122>(hj);
                    accA = pk_fma(whh_rot[2], splat2(h2), accA);
                    float h3 = dppf<0x123>(hj);
                    accB = pk_fma(whh_rot[3], splat2(h3), accB);
                    float h4 = dppf<0x124>(hj);
                    accA = pk_fma(whh_rot[4], splat2(h4), accA);
                    float h5 = dppf<0x125>(hj);
                    accB = pk_fma(whh_rot[5], splat2(h5), accB);
                    float h6 = dppf<0x126>(hj);
                    accA = pk_fma(whh_rot[6], splat2(h6), accA);
                    float h7 = dppf<0x127>(hj);
                    accB = pk_fma(whh_rot[7], splat2(h7), accB);
                }
                v2f accH = accA + accB;      // matvec lanes: (g0,g1) scaled
                                             // head lanes: (head0, head1) raw

                // input projection (zeroed on head lanes)
                v2f accP = biasP;
                #pragma unroll
                for (int i = 0; i < INn; ++i)
                    accP = pk_fma(wih01[i], splat2(xcf[5 * ss + i]), accP);

                // head(h_{s-1}) -> LDS ring slot tt (output index tl*32+tt-1);
                // offsets are compile-time -> single ds_write2_b32.
                if (hl) {
                    hwb[tt]      = accH[0];
                    hwb[33 + tt] = accH[1];
                }

                // gates: preacts arrive pre-scaled by -log2e / -2log2e
                float ea = __builtin_amdgcn_exp2f(accH[0] + accP[0]);
                float s  = __builtin_amdgcn_rcpf(1.0f + ea);
                float sv = dppf<0x128>(s);       // row_ror:8 half-swap
                float rv = lo8 ? s : sv;
                float zv = lo8 ? sv : s;
                float et = __builtin_amdgcn_exp2f(fmaf(rv, accH[1], accP[1]));
                float t  = __builtin_amdgcn_rcpf(1.0f + et);
                float n  = fmaf(2.0f, t, -1.0f); // tanh
                hj = n + zv * (hj - n);          // (1-z)*n + z*h
            }
        }

        // ---- flush head ring: output indices tl*32-1 .. tl*32+30 ----
        // same-wave LDS ordering: writes above are older, reads here wait
        // lgkmcnt; next tile's writes are newer. Coalesced stores: instr i
        // writes 16 consecutive dwords per group.
        {
            float* omt = om + tl * 96 - 3;
            float* ort = orr + tl * 32 - 1;
            #pragma unroll
            for (int i = 0; i < 6; ++i) {
                float v = hrd[fq[i]];
                if (tl > 0 || i > 0 || l >= 3) omt[i * 16 + l] = v;
            }
            float v0 = hrd[99 + l];
            float v1 = hrd[99 + 16 + l];
            if (tl > 0 || l > 0) ort[l] = v0;
            ort[16 + l] = v1;
        }
        cur ^= 1;
    }

    // epilogue: head of final h (one more rotation), stored at index T-1
    {
        v2f accA = biasH;
        v2f accB = (v2f){0.0f, 0.0f};
        accA = pk_fma(whh_rot[0], splat2(hj), accA);
        accB = pk_fma(whh_rot[1], splat2(dppf<0x121>(hj)), accB);
        accA = pk_fma(whh_rot[2], splat2(dppf<0x122>(hj)), accA);
        accB = pk_fma(whh_rot[3], splat2(dppf<0x123>(hj)), accB);
        accA = pk_fma(whh_rot[4], splat2(dppf<0x124>(hj)), accA);
        accB = pk_fma(whh_rot[5], splat2(dppf<0x125>(hj)), accB);
        accA = pk_fma(whh_rot[6], splat2(dppf<0x126>(hj)), accA);
        accB = pk_fma(whh_rot[7], splat2(dppf<0x127>(hj)), accB);
        v2f accH = accA + accB;
        if (hl)  om[(Tn - 1) * 3 + (lo8 ? 0 : 2)] = accH[0];
        if (hl && lo8) om[(Tn - 1) * 3 + 1] = accH[1];
        if (is15)      orr[Tn - 1]          = accH[1];
    }

    // h_last: [1, B, H]
    if (l < Hn) out[OFF_HL + (long long)b * Hn + l] = hj;
}

extern "C" void kernel_launch(void* const* d_in, const int* in_sizes, int n_in,
                              void* d_out, int out_size, void* d_ws, size_t ws_size,
                              hipStream_t stream) {
    const float* x    = (const float*)d_in[0];
    // d_in[1] = batch_size (scalar), unused — B compiled in
    const float* W_ih = (const float*)d_in[2];
    const float* W_hh = (const float*)d_in[3];
    const float* b_ih = (const float*)d_in[4];
    const float* b_hh = (const float*)d_in[5];
    const float* W_h0 = (const float*)d_in[6];
    const float* W_m  = (const float*)d_in[7];
    const float* b_m  = (const float*)d_in[8];
    const float* W_r  = (const float*)d_in[9];
    const float* b_r  = (const float*)d_in[10];
    float* out = (float*)d_out;

    dim3 grid(Bn / BPB);  // 512 blocks
    dim3 block(256);      // 16 batch elements x 16 lanes
    gru_fused_kernel<<<grid, block, 0, stream>>>(x, W_ih, W_hh, b_ih, b_hh,
                                                 W_h0, W_m, b_m, W_r, b_r, out);
}